// Round 8
// baseline (596.493 us; speedup 1.0000x reference)
//
#include <hip/hip_runtime.h>

typedef unsigned int u32;
typedef unsigned short u16;
typedef __attribute__((ext_vector_type(4))) float f32x4;
typedef __attribute__((ext_vector_type(8))) short bf16x8;
typedef __attribute__((ext_vector_type(4))) u32 u32x4;
typedef __attribute__((ext_vector_type(2))) u32 u32x2;

__device__ __forceinline__ u16 f2bf(float f) {
  u32 u = __builtin_bit_cast(u32, f);
  u = u + 0x7FFFu + ((u >> 16) & 1u);
  return (u16)(u >> 16);
}
__device__ __forceinline__ u32 pack2(float a, float b) {
  return (u32)f2bf(a) | ((u32)f2bf(b) << 16);
}
// Pack two C-frags into one A/B-frag under k-permutation
// sigma(u): g=u>>3, p=u&7 -> 16*(p>>2) + g*4 + (p&3)   (within each 32-chunk)
__device__ __forceinline__ bf16x8 pack8(f32x4 a, f32x4 b) {
  union { u32 w[4]; bf16x8 v; } u;
  u.w[0] = pack2(a[0], a[1]); u.w[1] = pack2(a[2], a[3]);
  u.w[2] = pack2(b[0], b[1]); u.w[3] = pack2(b[2], b[3]);
  return u.v;
}
// inverse of sigma: given ch-local c (0..31) return kappa-local u
__device__ __forceinline__ int finv5(int c) {
  return ((c >> 2) & 3) * 8 + ((c >> 4) << 2) + (c & 3);
}

#define MFMA(a, b, c) __builtin_amdgcn_mfma_f32_16x16x32_bf16((a), (b), (c), 0, 0, 0)

// window/token -> flat token index in [B,32,32,32]
__device__ __forceinline__ int tok_global(int blk, int t) {
  int b = blk >> 9, r = blk & 511;
  int wd = r >> 6, wh = (r >> 3) & 7, ww = r & 7;
  int d = wd * 4 + (t >> 4);
  int h = wh * 4 + ((t >> 2) & 3);
  int w = ww * 4 + (t & 3);
  return ((b * 32 + d) * 32 + h) * 32 + w;
}

// Weights: transpose + bf16 + sigma-permuted k order.
// wtq[o][kappa] = W_qkv[ch(kappa)][o], ch(kappa) = (kappa&~31) | sigma(kappa&31)
__global__ void prep_weights(const float* __restrict__ wq, const float* __restrict__ wp,
                             u16* __restrict__ wtq, u16* __restrict__ wtp) {
  int idx = blockIdx.x * 512 + threadIdx.x;
  if (idx < 512 * 1536) {
    int i = idx / 1536, o = idx % 1536;     // coalesced read of W_qkv[i][o]
    int kap = (i & ~31) | finv5(i & 31);
    wtq[o * 512 + kap] = f2bf(wq[idx]);
  } else {
    int j = idx - 512 * 1536;
    int i = j >> 9, o = j & 511;
    int kap = (i & ~31) | finv5(i & 31);
    wtp[o * 512 + kap] = f2bf(wp[j]);
  }
}

// x -> pre-packed B-frag blob: xb[win][ks16][j4][lane64] : bf16x8 (16B)
// frag elem u (=g*8+p) holds x[tok(win, j*16+lr)][ks*32 + sigma(u)], bf16.
// Thread reads 8 consecutive ch (32B, coalesced); writes two 8B halves.
__global__ void prep_x(const float* __restrict__ x, u32* __restrict__ xb) {
  int gid = blockIdx.x * 512 + threadIdx.x;      // (win, t, c8)
  int win = gid >> 12, t = (gid >> 6) & 63, c8 = gid & 63;
  int j = t >> 4, lr = t & 15;
  const float4* src = (const float4*)(x + (size_t)tok_global(win, t) * 512 + c8 * 8);
  float4 f0 = src[0], f1 = src[1];
  int ks = c8 >> 2, r = c8 & 3;
  int g0 = (r & 1) * 2;        // lanes g0, g0+1 get f0, f1
  int wo = (r >> 1) * 2;       // u32 word offset 0 or 2
  u32* base = xb + ((((size_t)win * 16 + ks) * 4 + j) * 64) * 4;
  u32x2 a = {pack2(f0.x, f0.y), pack2(f0.z, f0.w)};
  u32x2 b = {pack2(f1.x, f1.y), pack2(f1.z, f1.w)};
  *(u32x2*)(base + (g0 * 16 + lr) * 4 + wo) = a;
  *(u32x2*)(base + ((g0 + 1) * 16 + lr) * 4 + wo) = b;
}

// ===== Attention core: 4 independent (win,head) tasks per 256-thr block =====
// No LDS, no barriers. O written as pre-packed proj-B-frags:
// ob[((win*8+head)*4 + j)*2 + kb][lane] : bf16x8
__global__ __launch_bounds__(256, 3) void attn_core(
    const bf16x8* __restrict__ xb, const float* __restrict__ bq,
    const u16* __restrict__ wtq, bf16x8* __restrict__ ob) {
  const int tid = threadIdx.x;
  const int task = blockIdx.x * 4 + (tid >> 6);
  const int win = task >> 3, head = task & 7;
  const int l = tid & 63, lr = l & 15, g = l >> 4;
  const bf16x8* xw = xb + (size_t)win * 64;            // [ks][j][lane] (16*4*64... win*4096? see note)
  // NOTE: frag index = (ks*4 + j)*64 + l within a window; window stride = 16*4*64 = 4096
  const bf16x8* xwin = xb + (size_t)win * 4096;
  const u16* wq_lane = wtq + (size_t)(head * 64 + lr) * 512 + g * 8;
  const u16* wk_lane = wq_lane + (size_t)512 * 512;
  const u16* wv_lane = wq_lane + (size_t)1024 * 512;

  bf16x8 qp[4][2], ka[4][2], pb[4][2], va[4][2];

  // ---- Q pass: full 64 och (acc 64 regs) ----
  {
    f32x4 acc[4][4];
#pragma unroll
    for (int i = 0; i < 4; ++i)
#pragma unroll
      for (int j = 0; j < 4; ++j) acc[i][j] = (f32x4)0.f;
#pragma unroll
    for (int ks = 0; ks < 16; ++ks) {
      bf16x8 bx[4], wf[4];
#pragma unroll
      for (int j = 0; j < 4; ++j) bx[j] = xwin[(ks * 4 + j) * 64 + l];
#pragma unroll
      for (int i = 0; i < 4; ++i) wf[i] = *(const bf16x8*)(wq_lane + ks * 32 + i * 8192);
#pragma unroll
      for (int i = 0; i < 4; ++i)
#pragma unroll
        for (int j = 0; j < 4; ++j) acc[i][j] = MFMA(wf[i], bx[j], acc[i][j]);
    }
#pragma unroll
    for (int i = 0; i < 4; ++i) {
      const int och = head * 64 + i * 16 + g * 4;
      f32x4 qb = {bq[och], bq[och + 1], bq[och + 2], bq[och + 3]};
#pragma unroll
      for (int j = 0; j < 4; ++j) acc[i][j] += qb;
    }
#pragma unroll
    for (int j = 0; j < 4; ++j)
#pragma unroll
      for (int kb = 0; kb < 2; ++kb)
        qp[j][kb] = pack8(acc[2 * kb][j], acc[2 * kb + 1][j]);   // B-frag: col t, k=d
  }

  // ---- K pass: och-halved (acc 32 regs live) ----
#pragma unroll
  for (int kh = 0; kh < 2; ++kh) {
    f32x4 kacc[2][4];
#pragma unroll
    for (int i = 0; i < 2; ++i)
#pragma unroll
      for (int j = 0; j < 4; ++j) kacc[i][j] = (f32x4)0.f;
#pragma unroll
    for (int ks = 0; ks < 16; ++ks) {
      bf16x8 bx[4], wf[2];
#pragma unroll
      for (int j = 0; j < 4; ++j) bx[j] = xwin[(ks * 4 + j) * 64 + l];
#pragma unroll
      for (int i = 0; i < 2; ++i)
        wf[i] = *(const bf16x8*)(wk_lane + ks * 32 + (kh * 2 + i) * 8192);
#pragma unroll
      for (int i = 0; i < 2; ++i)
#pragma unroll
        for (int j = 0; j < 4; ++j) kacc[i][j] = MFMA(wf[i], bx[j], kacc[i][j]);
    }
#pragma unroll
    for (int i = 0; i < 2; ++i) {
      const int och = 512 + head * 64 + (kh * 2 + i) * 16 + g * 4;
      f32x4 kb = {bq[och], bq[och + 1], bq[och + 2], bq[och + 3]};
#pragma unroll
      for (int j = 0; j < 4; ++j) kacc[i][j] += kb;
    }
#pragma unroll
    for (int m = 0; m < 4; ++m)
      ka[m][kh] = pack8(kacc[0][m], kacc[1][m]);   // A-frag: row s, k=d
  }

  // ---- S^T + softmax, t-halved (sacc 32 regs) ----
#pragma unroll
  for (int h = 0; h < 2; ++h) {
    f32x4 sacc[4][2];
#pragma unroll
    for (int m = 0; m < 4; ++m)
#pragma unroll
      for (int jj = 0; jj < 2; ++jj) {
        const int j = 2 * h + jj;
        f32x4 a = (f32x4)0.f;
        a = MFMA(ka[m][0], qp[j][0], a);
        sacc[m][jj] = MFMA(ka[m][1], qp[j][1], a);
      }
#pragma unroll
    for (int m = 0; m < 4; ++m)
#pragma unroll
      for (int jj = 0; jj < 2; ++jj)
#pragma unroll
        for (int r = 0; r < 4; ++r) {
          float v = sacc[m][jj][r] * 0.125f;
          sacc[m][jj][r] = fminf(fmaxf(v, -10000.f), 10000.f);
        }
    float mx[2], sm[2];
#pragma unroll
    for (int jj = 0; jj < 2; ++jj) {
      float a0 = fmaxf(fmaxf(sacc[0][jj][0], sacc[0][jj][1]), fmaxf(sacc[0][jj][2], sacc[0][jj][3]));
      float a1 = fmaxf(fmaxf(sacc[1][jj][0], sacc[1][jj][1]), fmaxf(sacc[1][jj][2], sacc[1][jj][3]));
      float a2 = fmaxf(fmaxf(sacc[2][jj][0], sacc[2][jj][1]), fmaxf(sacc[2][jj][2], sacc[2][jj][3]));
      float a3 = fmaxf(fmaxf(sacc[3][jj][0], sacc[3][jj][1]), fmaxf(sacc[3][jj][2], sacc[3][jj][3]));
      mx[jj] = fmaxf(fmaxf(a0, a1), fmaxf(a2, a3));
    }
#pragma unroll
    for (int jj = 0; jj < 2; ++jj) mx[jj] = fmaxf(mx[jj], __shfl_xor(mx[jj], 16));
#pragma unroll
    for (int jj = 0; jj < 2; ++jj) mx[jj] = fmaxf(mx[jj], __shfl_xor(mx[jj], 32));
#pragma unroll
    for (int jj = 0; jj < 2; ++jj) {
      float s0 = 0.f;
#pragma unroll
      for (int m = 0; m < 4; ++m)
#pragma unroll
        for (int r = 0; r < 4; ++r) {
          float p = __expf(sacc[m][jj][r] - mx[jj]);
          sacc[m][jj][r] = p;
          s0 += p;
        }
      sm[jj] = s0;
    }
#pragma unroll
    for (int jj = 0; jj < 2; ++jj) sm[jj] += __shfl_xor(sm[jj], 16);
#pragma unroll
    for (int jj = 0; jj < 2; ++jj) sm[jj] += __shfl_xor(sm[jj], 32);
#pragma unroll
    for (int jj = 0; jj < 2; ++jj) {
      float inv = 1.f / sm[jj];
#pragma unroll
      for (int kb = 0; kb < 2; ++kb)
        pb[2 * h + jj][kb] = pack8(sacc[2 * kb][jj] * inv, sacc[2 * kb + 1][jj] * inv);
    }
  }

  // ---- V pass: full (vacc 64) ----
  {
    f32x4 vacc[4][4];
#pragma unroll
    for (int i = 0; i < 4; ++i)
#pragma unroll
      for (int j = 0; j < 4; ++j) vacc[i][j] = (f32x4)0.f;
#pragma unroll
    for (int ks = 0; ks < 16; ++ks) {
      bf16x8 bx[4], wf[4];
#pragma unroll
      for (int ti = 0; ti < 4; ++ti) bx[ti] = xwin[(ks * 4 + ti) * 64 + l];
#pragma unroll
      for (int ni = 0; ni < 4; ++ni) wf[ni] = *(const bf16x8*)(wv_lane + ks * 32 + ni * 8192);
#pragma unroll
      for (int ti = 0; ti < 4; ++ti)
#pragma unroll
        for (int ni = 0; ni < 4; ++ni) vacc[ti][ni] = MFMA(bx[ti], wf[ni], vacc[ti][ni]);
    }
#pragma unroll
    for (int ni = 0; ni < 4; ++ni) {
      float bv = bq[1024 + head * 64 + ni * 16 + lr];
#pragma unroll
      for (int ti = 0; ti < 4; ++ti) vacc[ti][ni] += (f32x4)bv;
#pragma unroll
      for (int kb = 0; kb < 2; ++kb)
        va[ni][kb] = pack8(vacc[2 * kb][ni], vacc[2 * kb + 1][ni]);  // A-frag: row d, k=s
    }
  }

  // ---- O^T = V^T x P^T ; write packed proj-B-frags ----
  bf16x8* obase = ob + ((size_t)(win * 8 + head) * 4) * 2 * 64;
#pragma unroll
  for (int j = 0; j < 4; ++j) {
    f32x4 o0 = (f32x4)0.f, o1 = (f32x4)0.f, o2 = (f32x4)0.f, o3 = (f32x4)0.f;
    o0 = MFMA(va[0][0], pb[j][0], o0); o0 = MFMA(va[0][1], pb[j][1], o0);
    o1 = MFMA(va[1][0], pb[j][0], o1); o1 = MFMA(va[1][1], pb[j][1], o1);
    o2 = MFMA(va[2][0], pb[j][0], o2); o2 = MFMA(va[2][1], pb[j][1], o2);
    o3 = MFMA(va[3][0], pb[j][0], o3); o3 = MFMA(va[3][1], pb[j][1], o3);
    obase[(j * 2 + 0) * 64 + l] = pack8(o0, o1);   // kb=0 : d 0..31
    obase[(j * 2 + 1) * 64 + l] = pack8(o2, o3);   // kb=1 : d 32..63
  }
}

// ===== Proj GEMM: Y = O @ Wproj, reads packed O-frags, no LDS =====
__global__ __launch_bounds__(512, 4) void proj_gemm(
    const bf16x8* __restrict__ ob, const u16* __restrict__ wtp,
    const float* __restrict__ bp, float* __restrict__ out) {
  const int tid = threadIdx.x, wv = tid >> 6, l = tid & 63, lr = l & 15, g = l >> 4;
  const int win = blockIdx.x;
  const u16* wp_lane = wtp + (size_t)(wv * 64 + lr) * 512 + g * 8;
  const bf16x8* obase = ob + (size_t)win * 8 * 4 * 2 * 64;
  f32x4 acc[4][4];
#pragma unroll
  for (int i = 0; i < 4; ++i)
#pragma unroll
    for (int j = 0; j < 4; ++j) acc[i][j] = (f32x4)0.f;
#pragma unroll
  for (int ks = 0; ks < 16; ++ks) {     // ks = h*2 + kb
    bf16x8 bx[4], wa[4];
#pragma unroll
    for (int j = 0; j < 4; ++j)
      bx[j] = obase[((ks >> 1) * 4 + j) * 128 + (ks & 1) * 64 + l];
#pragma unroll
    for (int i = 0; i < 4; ++i) wa[i] = *(const bf16x8*)(wp_lane + ks * 32 + i * 8192);
#pragma unroll
    for (int i = 0; i < 4; ++i)
#pragma unroll
      for (int j = 0; j < 4; ++j) acc[i][j] = MFMA(wa[i], bx[j], acc[i][j]);
  }
#pragma unroll
  for (int mi = 0; mi < 4; ++mi) {
    const int och = wv * 64 + mi * 16 + g * 4;
    float b0 = bp[och], b1 = bp[och + 1], b2 = bp[och + 2], b3 = bp[och + 3];
#pragma unroll
    for (int tj = 0; tj < 4; ++tj) {
      int t = tj * 16 + lr;
      f32x4 v = acc[mi][tj];
      float4 o;
      o.x = v[0] + b0; o.y = v[1] + b1; o.z = v[2] + b2; o.w = v[3] + b3;
      *(float4*)(out + (size_t)tok_global(win, t) * 512 + och) = o;
    }
  }
}

extern "C" void kernel_launch(void* const* d_in, const int* in_sizes, int n_in,
                              void* d_out, int out_size, void* d_ws, size_t ws_size,
                              hipStream_t stream) {
  const float* x  = (const float*)d_in[0];
  const float* wq = (const float*)d_in[1];
  const float* bq = (const float*)d_in[2];
  const float* wp = (const float*)d_in[3];
  const float* bp = (const float*)d_in[4];
  float* out = (float*)d_out;

  // Workspace: weights (2MB) + O-blob (64MB). x-blob lives in d_out[0,64MB)
  // (read by attn_core, then fully overwritten by proj_gemm afterwards).
  u16* wtq = (u16*)d_ws;                               // [1536][512] bf16, sigma-k
  u16* wtp = wtq + 512 * 1536;                         // [512][512]
  bf16x8* ob = (bf16x8*)((char*)d_ws + 2 * 1024 * 1024);  // 4.19M frags = 64MB
  bf16x8* xbv = (bf16x8*)d_out;                        // 4.19M frags = 64MB

  prep_weights<<<2048, 512, 0, stream>>>(wq, wp, wtq, wtp);
  prep_x<<<8192, 512, 0, stream>>>(x, (u32*)d_out);
  attn_core<<<2048, 256, 0, stream>>>(xbv, bq, wtq, ob);
  proj_gemm<<<1024, 512, 0, stream>>>(ob, wtp, bp, out);
}

// Round 10
// 226.819 us; speedup vs baseline: 2.6298x; 2.6298x over previous
//
#include <hip/hip_runtime.h>

typedef unsigned int u32;
typedef unsigned short u16;
typedef __attribute__((ext_vector_type(4))) float f32x4;
typedef __attribute__((ext_vector_type(8))) short bf16x8;
typedef __attribute__((ext_vector_type(4))) u32 u32x4;

__device__ __forceinline__ u16 f2bf(float f) {
  u32 u = __builtin_bit_cast(u32, f);
  u = u + 0x7FFFu + ((u >> 16) & 1u);
  return (u16)(u >> 16);
}
__device__ __forceinline__ u32 pack2(float a, float b) {
  return (u32)f2bf(a) | ((u32)f2bf(b) << 16);
}
// Pack two C-frags (f32x4 each) into one A/B-frag under the consistent
// k-permutation sigma(8g+p) = 16*(p>>2) + g*4 + (p&3) (+32*kb outside).
// Valid because BOTH operands of the attention-middle MFMAs are packed
// with the same sigma (Q&K for S^T; V&P for O^T).
__device__ __forceinline__ bf16x8 pack8(f32x4 a, f32x4 b) {
  union { u32 w[4]; bf16x8 v; } u;
  u.w[0] = pack2(a[0], a[1]); u.w[1] = pack2(a[2], a[3]);
  u.w[2] = pack2(b[0], b[1]); u.w[3] = pack2(b[2], b[3]);
  return u.v;
}

#define MFMA(a, b, c) __builtin_amdgcn_mfma_f32_16x16x32_bf16((a), (b), (c), 0, 0, 0)

// LDS fragment read: row-major buffer, XOR-swizzled within 128B window.
__device__ __forceinline__ bf16x8 lds_frag(const char* buf, int rowBytes, int row, int kByte) {
  return *(const bf16x8*)(buf + row * rowBytes + (kByte ^ ((row & 7) << 4)));
}

// window/token -> flat token index in [B,32,32,32] (C-contiguous per token)
__device__ __forceinline__ int tok_global(int blk, int t) {
  int b = blk >> 9, r = blk & 511;
  int wd = r >> 6, wh = (r >> 3) & 7, ww = r & 7;
  int d = wd * 4 + (t >> 4);
  int h = wh * 4 + ((t >> 2) & 3);
  int w = ww * 4 + (t & 3);
  return ((b * 32 + d) * 32 + h) * 32 + w;
}

// Weights -> FRAG-MAJOR blob, NATURAL k order within each 32-chunk:
// w[(o_blk*16 + ks)*512 + lane*8 + p] = bf16 of W[ks*32 + g*8 + p][o_blk*16 + lr],
// lane = g*16 + lr. This matches the HW A/B-frag mapping (row/col = lane&15,
// k = (lane>>4)*8 + p), with x read from LDS in natural channel order.
// A wave's frag load = base + lane*8 -> 16B/lane, 1KB contiguous (ideal).
__global__ void prep_weights(const float* __restrict__ wq, const float* __restrict__ wp,
                             u16* __restrict__ wtq, u16* __restrict__ wtp) {
  int idx = blockIdx.x * 512 + threadIdx.x;
  if (idx < 512 * 1536) {
    int i = idx / 1536, o = idx % 1536;     // coalesced read of W_qkv[i][o]
    int c = i & 31;                          // k-local, natural order
    int lane = (c >> 3) * 16 + (o & 15);
    wtq[((size_t)(o >> 4) * 16 + (i >> 5)) * 512 + lane * 8 + (c & 7)] = f2bf(wq[idx]);
  } else {
    int j = idx - 512 * 1536;
    int i = j >> 9, o = j & 511;
    int c = i & 31;
    int lane = (c >> 3) * 16 + (o & 15);
    wtp[((size_t)(o >> 4) * 16 + (i >> 5)) * 512 + lane * 8 + (c & 7)] = f2bf(wp[j]);
  }
}

// GEMM pass over 16 K-steps. Weight frags prefetched depth-2 in 3 static
// slots; frag address = WLANE + (i*16 + ks)*512 (u16), coalesced 1KB/instr.
#define GEMM_PASS_AB(WLANE, SMEMBASE)                                         \
  {                                                                           \
    bf16x8 wfs[3][4];                                                         \
    _Pragma("unroll") for (int i = 0; i < 4; ++i)                             \
        wfs[0][i] = *(const bf16x8*)((WLANE) + (i * 16 + 0) * 512);           \
    _Pragma("unroll") for (int i = 0; i < 4; ++i)                             \
        wfs[1][i] = *(const bf16x8*)((WLANE) + (i * 16 + 1) * 512);           \
    _Pragma("unroll") for (int ks = 0; ks < 16; ++ks) {                       \
      if (ks < 14) {                                                          \
        _Pragma("unroll") for (int i = 0; i < 4; ++i)                         \
            wfs[(ks + 2) % 3][i] =                                            \
                *(const bf16x8*)((WLANE) + (i * 16 + ks + 2) * 512);          \
      }                                                                       \
      bf16x8 bx[4];                                                           \
      const int kByte = ks * 64 + g * 16;                                     \
      _Pragma("unroll") for (int j = 0; j < 4; ++j)                           \
          bx[j] = lds_frag((SMEMBASE), 1024, j * 16 + lr, kByte);             \
      __builtin_amdgcn_s_setprio(1);                                          \
      _Pragma("unroll") for (int i = 0; i < 4; ++i)                           \
        _Pragma("unroll") for (int j = 0; j < 4; ++j)                         \
            acc[i][j] = MFMA(wfs[ks % 3][i], bx[j], acc[i][j]);               \
      __builtin_amdgcn_s_setprio(0);                                          \
    }                                                                         \
  }
#define GEMM_PASS_BA(WLANE, SMEMBASE)                                         \
  {                                                                           \
    bf16x8 wfs[3][4];                                                         \
    _Pragma("unroll") for (int i = 0; i < 4; ++i)                             \
        wfs[0][i] = *(const bf16x8*)((WLANE) + (i * 16 + 0) * 512);           \
    _Pragma("unroll") for (int i = 0; i < 4; ++i)                             \
        wfs[1][i] = *(const bf16x8*)((WLANE) + (i * 16 + 1) * 512);           \
    _Pragma("unroll") for (int ks = 0; ks < 16; ++ks) {                       \
      if (ks < 14) {                                                          \
        _Pragma("unroll") for (int i = 0; i < 4; ++i)                         \
            wfs[(ks + 2) % 3][i] =                                            \
                *(const bf16x8*)((WLANE) + (i * 16 + ks + 2) * 512);          \
      }                                                                       \
      bf16x8 bx[4];                                                           \
      const int kByte = ks * 64 + g * 16;                                     \
      _Pragma("unroll") for (int j = 0; j < 4; ++j)                           \
          bx[j] = lds_frag((SMEMBASE), 1024, j * 16 + lr, kByte);             \
      __builtin_amdgcn_s_setprio(1);                                          \
      _Pragma("unroll") for (int i = 0; i < 4; ++i)                           \
        _Pragma("unroll") for (int j = 0; j < 4; ++j)                         \
            acc[i][j] = MFMA(bx[i], wfs[ks % 3][j], acc[i][j]);               \
      __builtin_amdgcn_s_setprio(0);                                          \
    }                                                                         \
  }

__global__ __launch_bounds__(512, 2) void fused_win_attn(
    const float* __restrict__ x, const float* __restrict__ bq, const float* __restrict__ bp,
    const u16* __restrict__ wtq, const u16* __restrict__ wtp, float* __restrict__ out) {
  // LDS: x [64 tok][512 ch] bf16, XOR-swizzled; reused as O (same layout) after V pass.
  __shared__ char smem[65536];
  const int tid = threadIdx.x;
  const int wv = tid >> 6;   // wave id == head id
  const int l  = tid & 63;
  const int lr = l & 15;
  const int g  = l >> 4;
  const int blk = blockIdx.x;

  // ---- stage x -> LDS bf16 (once; 1 barrier). seg-rotation vs bank conflicts. ----
  {
    const int st = tid >> 3, seg = tid & 7;       // token row, 64-ch segment
    const float* xs = x + (size_t)tok_global(blk, st) * 512 + seg * 64;
    char* dst = smem + st * 1024;
    const int swz = (st & 7) << 4;
    float4 f[16];
#pragma unroll
    for (int i = 0; i < 16; ++i) f[i] = ((const float4*)xs)[i];
#pragma unroll
    for (int i = 0; i < 8; ++i) {
      const int ic = (i + seg) & 7;   // rotate so each phase spans all 32 banks
      u32x4 w = {pack2(f[2 * ic].x, f[2 * ic].y),         pack2(f[2 * ic].z, f[2 * ic].w),
                 pack2(f[2 * ic + 1].x, f[2 * ic + 1].y), pack2(f[2 * ic + 1].z, f[2 * ic + 1].w)};
      *(u32x4*)(dst + ((seg * 128 + ic * 16) ^ swz)) = w;
    }
  }
  __syncthreads();

  // per-lane weight base pointers into the frag-major blobs
  const u16* wqL = wtq + ((size_t)wv * 4 * 16) * 512 + l * 8;
  const u16* wkL = wqL + (size_t)512 * 512;    // +32 o_blks (och +512)
  const u16* wvL = wqL + (size_t)1024 * 512;   // +64 o_blks (och +1024)
  const u16* wpL = wtp + ((size_t)wv * 4 * 16) * 512 + l * 8;

  bf16x8 qp[4][2], ka[4][2], pb[4][2], va[4][2];
  f32x4 acc[4][4];

  // ======== Q pass: Q [d=64][t=64] (M=och, N=t, K=ch 512) ========
#pragma unroll
  for (int i = 0; i < 4; ++i)
#pragma unroll
    for (int j = 0; j < 4; ++j) acc[i][j] = (f32x4)0.f;
  GEMM_PASS_AB(wqL, smem);
#pragma unroll
  for (int i = 0; i < 4; ++i) {
    const int och = wv * 64 + i * 16 + g * 4;
    f32x4 qb = {bq[och], bq[och + 1], bq[och + 2], bq[och + 3]};
#pragma unroll
    for (int j = 0; j < 4; ++j) acc[i][j] += qb;
  }
#pragma unroll
  for (int j = 0; j < 4; ++j)
#pragma unroll
    for (int kb = 0; kb < 2; ++kb)
      qp[j][kb] = pack8(acc[2 * kb][j], acc[2 * kb + 1][j]);   // B-frag: col t, k=d

  // ======== K pass ========
#pragma unroll
  for (int i = 0; i < 4; ++i)
#pragma unroll
    for (int j = 0; j < 4; ++j) acc[i][j] = (f32x4)0.f;
  GEMM_PASS_AB(wkL, smem);
#pragma unroll
  for (int i = 0; i < 4; ++i) {
    const int och = 512 + wv * 64 + i * 16 + g * 4;
    f32x4 kb = {bq[och], bq[och + 1], bq[och + 2], bq[och + 3]};
#pragma unroll
    for (int j = 0; j < 4; ++j) acc[i][j] += kb;
  }
#pragma unroll
  for (int m = 0; m < 4; ++m)
#pragma unroll
    for (int kb = 0; kb < 2; ++kb)
      ka[m][kb] = pack8(acc[2 * kb][m], acc[2 * kb + 1][m]);   // A-frag: row s, k=d

  // ======== S^T = K-rows x Q (M=s, N=t, K=d=64): pure register MFMA ========
  {
    f32x4 sacc[4][4];
#pragma unroll
    for (int m = 0; m < 4; ++m)
#pragma unroll
      for (int j = 0; j < 4; ++j) {
        f32x4 a = (f32x4)0.f;
        a = MFMA(ka[m][0], qp[j][0], a);
        sacc[m][j] = MFMA(ka[m][1], qp[j][1], a);
      }
    // scale + clip + softmax over s (16 local + xor16 + xor32)
#pragma unroll
    for (int m = 0; m < 4; ++m)
#pragma unroll
      for (int j = 0; j < 4; ++j)
#pragma unroll
        for (int r = 0; r < 4; ++r) {
          float v = sacc[m][j][r] * 0.125f;
          sacc[m][j][r] = fminf(fmaxf(v, -10000.f), 10000.f);
        }
    float mx[4], sm[4];
#pragma unroll
    for (int j = 0; j < 4; ++j) {
      float a0 = fmaxf(fmaxf(sacc[0][j][0], sacc[0][j][1]), fmaxf(sacc[0][j][2], sacc[0][j][3]));
      float a1 = fmaxf(fmaxf(sacc[1][j][0], sacc[1][j][1]), fmaxf(sacc[1][j][2], sacc[1][j][3]));
      float a2 = fmaxf(fmaxf(sacc[2][j][0], sacc[2][j][1]), fmaxf(sacc[2][j][2], sacc[2][j][3]));
      float a3 = fmaxf(fmaxf(sacc[3][j][0], sacc[3][j][1]), fmaxf(sacc[3][j][2], sacc[3][j][3]));
      mx[j] = fmaxf(fmaxf(a0, a1), fmaxf(a2, a3));
    }
#pragma unroll
    for (int j = 0; j < 4; ++j) mx[j] = fmaxf(mx[j], __shfl_xor(mx[j], 16));
#pragma unroll
    for (int j = 0; j < 4; ++j) mx[j] = fmaxf(mx[j], __shfl_xor(mx[j], 32));
#pragma unroll
    for (int j = 0; j < 4; ++j) {
      float s0 = 0.f;
#pragma unroll
      for (int m = 0; m < 4; ++m)
#pragma unroll
        for (int r = 0; r < 4; ++r) {
          float p = __expf(sacc[m][j][r] - mx[j]);
          sacc[m][j][r] = p;
          s0 += p;
        }
      sm[j] = s0;
    }
#pragma unroll
    for (int j = 0; j < 4; ++j) sm[j] += __shfl_xor(sm[j], 16);
#pragma unroll
    for (int j = 0; j < 4; ++j) sm[j] += __shfl_xor(sm[j], 32);
#pragma unroll
    for (int j = 0; j < 4; ++j) {
      float inv = 1.f / sm[j];
#pragma unroll
      for (int kb = 0; kb < 2; ++kb)
        pb[j][kb] = pack8(sacc[2 * kb][j] * inv, sacc[2 * kb + 1][j] * inv);  // B-frag
    }
  }

  // ======== V pass: V [s=64][d=64] (M=t(=s), N=d, K=ch 512) ========
#pragma unroll
  for (int i = 0; i < 4; ++i)
#pragma unroll
    for (int j = 0; j < 4; ++j) acc[i][j] = (f32x4)0.f;
  GEMM_PASS_BA(wvL, smem);
#pragma unroll
  for (int ni = 0; ni < 4; ++ni) {
    float bv = bq[1024 + wv * 64 + ni * 16 + lr];
#pragma unroll
    for (int ti = 0; ti < 4; ++ti) acc[ti][ni] += (f32x4)bv;
#pragma unroll
    for (int kb = 0; kb < 2; ++kb)
      va[ni][kb] = pack8(acc[2 * kb][ni], acc[2 * kb + 1][ni]);  // A-frag: row d, k=s
  }

  // ---- all x reads done; switch LDS to O [t][512] bf16 ----
  __syncthreads();

  // ======== O^T = V^T x P^T (M=d, N=t, K=s=64) + write O to LDS ========
#pragma unroll
  for (int ni = 0; ni < 4; ++ni)
#pragma unroll
    for (int j = 0; j < 4; ++j) {
      f32x4 a = (f32x4)0.f;
      a = MFMA(va[ni][0], pb[j][0], a);
      a = MFMA(va[ni][1], pb[j][1], a);
      int t = j * 16 + lr;
      int cb = (wv * 64 + ni * 16 + g * 4) * 2;
      int swz = (t & 7) << 4;
      *(u32*)(smem + t * 1024 + (cb ^ swz))       = pack2(a[0], a[1]);
      *(u32*)(smem + t * 1024 + ((cb + 4) ^ swz)) = pack2(a[2], a[3]);
    }
  __syncthreads();

  // ======== Y = O @ Wproj (M=och, N=t, K=ch 512) ========
#pragma unroll
  for (int i = 0; i < 4; ++i)
#pragma unroll
    for (int j = 0; j < 4; ++j) acc[i][j] = (f32x4)0.f;
  GEMM_PASS_AB(wpL, smem);
  // epilogue: +bias, coalesced float4 scatter to output
#pragma unroll
  for (int mi = 0; mi < 4; ++mi) {
    const int och = wv * 64 + mi * 16 + g * 4;
    float b0 = bp[och], b1 = bp[och + 1], b2 = bp[och + 2], b3 = bp[och + 3];
#pragma unroll
    for (int tj = 0; tj < 4; ++tj) {
      int t = tj * 16 + lr;
      f32x4 v = acc[mi][tj];
      float4 o;
      o.x = v[0] + b0; o.y = v[1] + b1; o.z = v[2] + b2; o.w = v[3] + b3;
      *(float4*)(out + (size_t)tok_global(blk, t) * 512 + och) = o;
    }
  }
}

extern "C" void kernel_launch(void* const* d_in, const int* in_sizes, int n_in,
                              void* d_out, int out_size, void* d_ws, size_t ws_size,
                              hipStream_t stream) {
  const float* x  = (const float*)d_in[0];
  const float* wq = (const float*)d_in[1];
  const float* bq = (const float*)d_in[2];
  const float* wp = (const float*)d_in[3];
  const float* bp = (const float*)d_in[4];
  float* out = (float*)d_out;
  u16* wtq = (u16*)d_ws;            // qkv frag-major blob: 96 o_blks x 16 ks x 512
  u16* wtp = wtq + 512 * 1536;      // proj frag-major blob: 32 o_blks x 16 ks x 512

  prep_weights<<<2048, 512, 0, stream>>>(wq, wp, wtq, wtp);
  fused_win_attn<<<1024, 512, 0, stream>>>(x, bq, bp, wtq, wtp, out);
}

// Round 11
// 222.986 us; speedup vs baseline: 2.6750x; 1.0172x over previous
//
#include <hip/hip_runtime.h>

typedef unsigned int u32;
typedef unsigned short u16;
typedef __attribute__((ext_vector_type(4))) float f32x4;
typedef __attribute__((ext_vector_type(8))) short bf16x8;
typedef __attribute__((ext_vector_type(4))) u32 u32x4;

__device__ __forceinline__ u16 f2bf(float f) {
  u32 u = __builtin_bit_cast(u32, f);
  u = u + 0x7FFFu + ((u >> 16) & 1u);
  return (u16)(u >> 16);
}
__device__ __forceinline__ u32 pack2(float a, float b) {
  return (u32)f2bf(a) | ((u32)f2bf(b) << 16);
}
// Pack two C-frags (f32x4 each) into one A/B-frag under the consistent
// k-permutation sigma(8g+p) = 16*(p>>2) + g*4 + (p&3) (+32*kb outside).
// Valid because BOTH operands of the attention-middle MFMAs are packed
// with the same sigma (Q&K for S^T; V&P for O^T).
__device__ __forceinline__ bf16x8 pack8(f32x4 a, f32x4 b) {
  union { u32 w[4]; bf16x8 v; } u;
  u.w[0] = pack2(a[0], a[1]); u.w[1] = pack2(a[2], a[3]);
  u.w[2] = pack2(b[0], b[1]); u.w[3] = pack2(b[2], b[3]);
  return u.v;
}

#define MFMA(a, b, c) __builtin_amdgcn_mfma_f32_16x16x32_bf16((a), (b), (c), 0, 0, 0)

// LDS fragment read: row-major buffer, XOR-swizzled within 128B window.
__device__ __forceinline__ bf16x8 lds_frag(const char* buf, int rowBytes, int row, int kByte) {
  return *(const bf16x8*)(buf + row * rowBytes + (kByte ^ ((row & 7) << 4)));
}

// window/token -> flat token index in [B,32,32,32] (C-contiguous per token)
__device__ __forceinline__ int tok_global(int blk, int t) {
  int b = blk >> 9, r = blk & 511;
  int wd = r >> 6, wh = (r >> 3) & 7, ww = r & 7;
  int d = wd * 4 + (t >> 4);
  int h = wh * 4 + ((t >> 2) & 3);
  int w = ww * 4 + (t & 3);
  return ((b * 32 + d) * 32 + h) * 32 + w;
}

// Weights -> FRAG-MAJOR blob, NATURAL k order within each 32-chunk:
// w[(o_blk*16 + ks)*512 + lane*8 + p] = bf16 of W[ks*32 + g*8 + p][o_blk*16 + lr],
// lane = g*16 + lr. Matches HW A/B-frag mapping (row/col = lane&15,
// k = (lane>>4)*8 + p). Wave frag load = base + lane*8 -> 1KB contiguous.
__global__ void prep_weights(const float* __restrict__ wq, const float* __restrict__ wp,
                             u16* __restrict__ wtq, u16* __restrict__ wtp) {
  int idx = blockIdx.x * 512 + threadIdx.x;
  if (idx < 512 * 1536) {
    int i = idx / 1536, o = idx % 1536;     // coalesced read of W_qkv[i][o]
    int c = i & 31;                          // k-local, natural order
    int lane = (c >> 3) * 16 + (o & 15);
    wtq[((size_t)(o >> 4) * 16 + (i >> 5)) * 512 + lane * 8 + (c & 7)] = f2bf(wq[idx]);
  } else {
    int j = idx - 512 * 1536;
    int i = j >> 9, o = j & 511;
    int c = i & 31;
    int lane = (c >> 3) * 16 + (o & 15);
    wtp[((size_t)(o >> 4) * 16 + (i >> 5)) * 512 + lane * 8 + (c & 7)] = f2bf(wp[j]);
  }
}

// GEMM pass over 16 K-steps. Weight frags: depth-2 prefetch, 3 static slots
// (48 VGPR), coalesced 1KB/instr. x frags: depth-1 LDS prefetch, 2 static
// slots (32 VGPR) so ds_read latency hides under previous step's MFMAs.
#define GEMM_PASS_AB(WLANE, SMEMBASE)                                         \
  {                                                                           \
    bf16x8 wfs[3][4], bxs[2][4];                                              \
    _Pragma("unroll") for (int i = 0; i < 4; ++i)                             \
        wfs[0][i] = *(const bf16x8*)((WLANE) + (i * 16 + 0) * 512);           \
    _Pragma("unroll") for (int i = 0; i < 4; ++i)                             \
        wfs[1][i] = *(const bf16x8*)((WLANE) + (i * 16 + 1) * 512);           \
    _Pragma("unroll") for (int j = 0; j < 4; ++j)                             \
        bxs[0][j] = lds_frag((SMEMBASE), 1024, j * 16 + lr, g * 16);          \
    _Pragma("unroll") for (int ks = 0; ks < 16; ++ks) {                       \
      if (ks < 15) {                                                          \
        const int kb1 = (ks + 1) * 64 + g * 16;                               \
        _Pragma("unroll") for (int j = 0; j < 4; ++j)                         \
            bxs[(ks + 1) & 1][j] =                                            \
                lds_frag((SMEMBASE), 1024, j * 16 + lr, kb1);                 \
      }                                                                       \
      if (ks < 14) {                                                          \
        _Pragma("unroll") for (int i = 0; i < 4; ++i)                         \
            wfs[(ks + 2) % 3][i] =                                            \
                *(const bf16x8*)((WLANE) + (i * 16 + ks + 2) * 512);          \
      }                                                                       \
      __builtin_amdgcn_s_setprio(1);                                          \
      _Pragma("unroll") for (int i = 0; i < 4; ++i)                           \
        _Pragma("unroll") for (int j = 0; j < 4; ++j)                         \
            acc[i][j] = MFMA(wfs[ks % 3][i], bxs[ks & 1][j], acc[i][j]);      \
      __builtin_amdgcn_s_setprio(0);                                          \
    }                                                                         \
  }
#define GEMM_PASS_BA(WLANE, SMEMBASE)                                         \
  {                                                                           \
    bf16x8 wfs[3][4], bxs[2][4];                                              \
    _Pragma("unroll") for (int i = 0; i < 4; ++i)                             \
        wfs[0][i] = *(const bf16x8*)((WLANE) + (i * 16 + 0) * 512);           \
    _Pragma("unroll") for (int i = 0; i < 4; ++i)                             \
        wfs[1][i] = *(const bf16x8*)((WLANE) + (i * 16 + 1) * 512);           \
    _Pragma("unroll") for (int j = 0; j < 4; ++j)                             \
        bxs[0][j] = lds_frag((SMEMBASE), 1024, j * 16 + lr, g * 16);          \
    _Pragma("unroll") for (int ks = 0; ks < 16; ++ks) {                       \
      if (ks < 15) {                                                          \
        const int kb1 = (ks + 1) * 64 + g * 16;                               \
        _Pragma("unroll") for (int j = 0; j < 4; ++j)                         \
            bxs[(ks + 1) & 1][j] =                                            \
                lds_frag((SMEMBASE), 1024, j * 16 + lr, kb1);                 \
      }                                                                       \
      if (ks < 14) {                                                          \
        _Pragma("unroll") for (int i = 0; i < 4; ++i)                         \
            wfs[(ks + 2) % 3][i] =                                            \
                *(const bf16x8*)((WLANE) + (i * 16 + ks + 2) * 512);          \
      }                                                                       \
      __builtin_amdgcn_s_setprio(1);                                          \
      _Pragma("unroll") for (int i = 0; i < 4; ++i)                           \
        _Pragma("unroll") for (int j = 0; j < 4; ++j)                         \
            acc[i][j] = MFMA(bxs[ks & 1][i], wfs[ks % 3][j], acc[i][j]);      \
      __builtin_amdgcn_s_setprio(0);                                          \
    }                                                                         \
  }

__global__ __launch_bounds__(512, 2) void fused_win_attn(
    const float* __restrict__ x, const float* __restrict__ bq, const float* __restrict__ bp,
    const u16* __restrict__ wtq, const u16* __restrict__ wtp, float* __restrict__ out) {
  // LDS: x [64 tok][512 ch] bf16 swizzled; -> O (same layout) after V pass;
  // -> Y staging [32 tok][512 ch] f32 (two halves) in the epilogue.
  __shared__ char smem[65536];
  const int tid = threadIdx.x;
  const int wv = tid >> 6;   // wave id == head id
  const int l  = tid & 63;
  const int lr = l & 15;
  const int g  = l >> 4;
  const int blk = blockIdx.x;

  // ---- stage x -> LDS bf16 (once; 1 barrier) ----
  {
    const int st = tid >> 3, seg = tid & 7;       // token row, 64-ch segment
    const float* xs = x + (size_t)tok_global(blk, st) * 512 + seg * 64;
    char* dst = smem + st * 1024;
    const int swz = (st & 7) << 4;
    float4 f[16];
#pragma unroll
    for (int i = 0; i < 16; ++i) f[i] = ((const float4*)xs)[i];
#pragma unroll
    for (int i = 0; i < 8; ++i) {
      const int ic = (i + seg) & 7;   // rotate across bank quads per phase
      u32x4 w = {pack2(f[2 * ic].x, f[2 * ic].y),         pack2(f[2 * ic].z, f[2 * ic].w),
                 pack2(f[2 * ic + 1].x, f[2 * ic + 1].y), pack2(f[2 * ic + 1].z, f[2 * ic + 1].w)};
      *(u32x4*)(dst + ((seg * 128 + ic * 16) ^ swz)) = w;
    }
  }
  __syncthreads();

  // per-lane weight base pointers into the frag-major blobs
  const u16* wqL = wtq + ((size_t)wv * 4 * 16) * 512 + l * 8;
  const u16* wkL = wqL + (size_t)512 * 512;    // +32 o_blks (och +512)
  const u16* wvL = wqL + (size_t)1024 * 512;   // +64 o_blks (och +1024)
  const u16* wpL = wtp + ((size_t)wv * 4 * 16) * 512 + l * 8;

  bf16x8 qp[4][2], ka[4][2], pb[4][2], va[4][2];
  f32x4 acc[4][4];

  // ======== Q pass: Q [d=64][t=64] (M=och, N=t, K=ch 512) ========
#pragma unroll
  for (int i = 0; i < 4; ++i)
#pragma unroll
    for (int j = 0; j < 4; ++j) acc[i][j] = (f32x4)0.f;
  GEMM_PASS_AB(wqL, smem);
#pragma unroll
  for (int i = 0; i < 4; ++i) {
    const int och = wv * 64 + i * 16 + g * 4;
    f32x4 qb = {bq[och], bq[och + 1], bq[och + 2], bq[och + 3]};
#pragma unroll
    for (int j = 0; j < 4; ++j) acc[i][j] += qb;
  }
#pragma unroll
  for (int j = 0; j < 4; ++j)
#pragma unroll
    for (int kb = 0; kb < 2; ++kb)
      qp[j][kb] = pack8(acc[2 * kb][j], acc[2 * kb + 1][j]);   // B-frag: col t, k=d

  // ======== K pass ========
#pragma unroll
  for (int i = 0; i < 4; ++i)
#pragma unroll
    for (int j = 0; j < 4; ++j) acc[i][j] = (f32x4)0.f;
  GEMM_PASS_AB(wkL, smem);
#pragma unroll
  for (int i = 0; i < 4; ++i) {
    const int och = 512 + wv * 64 + i * 16 + g * 4;
    f32x4 kb = {bq[och], bq[och + 1], bq[och + 2], bq[och + 3]};
#pragma unroll
    for (int j = 0; j < 4; ++j) acc[i][j] += kb;
  }
#pragma unroll
  for (int m = 0; m < 4; ++m)
#pragma unroll
    for (int kb = 0; kb < 2; ++kb)
      ka[m][kb] = pack8(acc[2 * kb][m], acc[2 * kb + 1][m]);   // A-frag: row s, k=d

  // ======== S^T = K-rows x Q (M=s, N=t, K=d=64): pure register MFMA ========
  {
    f32x4 sacc[4][4];
#pragma unroll
    for (int m = 0; m < 4; ++m)
#pragma unroll
      for (int j = 0; j < 4; ++j) {
        f32x4 a = (f32x4)0.f;
        a = MFMA(ka[m][0], qp[j][0], a);
        sacc[m][j] = MFMA(ka[m][1], qp[j][1], a);
      }
    // scale + clip + softmax over s (16 local + xor16 + xor32)
#pragma unroll
    for (int m = 0; m < 4; ++m)
#pragma unroll
      for (int j = 0; j < 4; ++j)
#pragma unroll
        for (int r = 0; r < 4; ++r) {
          float v = sacc[m][j][r] * 0.125f;
          sacc[m][j][r] = fminf(fmaxf(v, -10000.f), 10000.f);
        }
    float mx[4], sm[4];
#pragma unroll
    for (int j = 0; j < 4; ++j) {
      float a0 = fmaxf(fmaxf(sacc[0][j][0], sacc[0][j][1]), fmaxf(sacc[0][j][2], sacc[0][j][3]));
      float a1 = fmaxf(fmaxf(sacc[1][j][0], sacc[1][j][1]), fmaxf(sacc[1][j][2], sacc[1][j][3]));
      float a2 = fmaxf(fmaxf(sacc[2][j][0], sacc[2][j][1]), fmaxf(sacc[2][j][2], sacc[2][j][3]));
      float a3 = fmaxf(fmaxf(sacc[3][j][0], sacc[3][j][1]), fmaxf(sacc[3][j][2], sacc[3][j][3]));
      mx[j] = fmaxf(fmaxf(a0, a1), fmaxf(a2, a3));
    }
#pragma unroll
    for (int j = 0; j < 4; ++j) mx[j] = fmaxf(mx[j], __shfl_xor(mx[j], 16));
#pragma unroll
    for (int j = 0; j < 4; ++j) mx[j] = fmaxf(mx[j], __shfl_xor(mx[j], 32));
#pragma unroll
    for (int j = 0; j < 4; ++j) {
      float s0 = 0.f;
#pragma unroll
      for (int m = 0; m < 4; ++m)
#pragma unroll
        for (int r = 0; r < 4; ++r) {
          float p = __expf(sacc[m][j][r] - mx[j]);
          sacc[m][j][r] = p;
          s0 += p;
        }
      sm[j] = s0;
    }
#pragma unroll
    for (int j = 0; j < 4; ++j) sm[j] += __shfl_xor(sm[j], 16);
#pragma unroll
    for (int j = 0; j < 4; ++j) sm[j] += __shfl_xor(sm[j], 32);
#pragma unroll
    for (int j = 0; j < 4; ++j) {
      float inv = 1.f / sm[j];
#pragma unroll
      for (int kb = 0; kb < 2; ++kb)
        pb[j][kb] = pack8(sacc[2 * kb][j] * inv, sacc[2 * kb + 1][j] * inv);  // B-frag
    }
  }

  // ======== V pass: V [s=64][d=64] (M=t(=s), N=d, K=ch 512) ========
#pragma unroll
  for (int i = 0; i < 4; ++i)
#pragma unroll
    for (int j = 0; j < 4; ++j) acc[i][j] = (f32x4)0.f;
  GEMM_PASS_BA(wvL, smem);
#pragma unroll
  for (int ni = 0; ni < 4; ++ni) {
    float bv = bq[1024 + wv * 64 + ni * 16 + lr];
#pragma unroll
    for (int ti = 0; ti < 4; ++ti) acc[ti][ni] += (f32x4)bv;
#pragma unroll
    for (int kb = 0; kb < 2; ++kb)
      va[ni][kb] = pack8(acc[2 * kb][ni], acc[2 * kb + 1][ni]);  // A-frag: row d, k=s
  }

  // ---- all x reads done; switch LDS to O [t][512] bf16 ----
  __syncthreads();

  // ======== O^T = V^T x P^T (M=d, N=t, K=s=64) + write O to LDS ========
#pragma unroll
  for (int ni = 0; ni < 4; ++ni)
#pragma unroll
    for (int j = 0; j < 4; ++j) {
      f32x4 a = (f32x4)0.f;
      a = MFMA(va[ni][0], pb[j][0], a);
      a = MFMA(va[ni][1], pb[j][1], a);
      int t = j * 16 + lr;
      int cb = (wv * 64 + ni * 16 + g * 4) * 2;
      int swz = (t & 7) << 4;
      *(u32*)(smem + t * 1024 + (cb ^ swz))       = pack2(a[0], a[1]);
      *(u32*)(smem + t * 1024 + ((cb + 4) ^ swz)) = pack2(a[2], a[3]);
    }
  __syncthreads();

  // ======== Y = O @ Wproj (M=och, N=t, K=ch 512) ========
#pragma unroll
  for (int i = 0; i < 4; ++i)
#pragma unroll
    for (int j = 0; j < 4; ++j) acc[i][j] = (f32x4)0.f;
  GEMM_PASS_AB(wpL, smem);
  // +bias into acc
#pragma unroll
  for (int mi = 0; mi < 4; ++mi) {
    const int och = wv * 64 + mi * 16 + g * 4;
    f32x4 bb = {bp[och], bp[och + 1], bp[och + 2], bp[och + 3]};
#pragma unroll
    for (int tj = 0; tj < 4; ++tj) acc[mi][tj] += bb;
  }

  // ======== Epilogue: stage Y via LDS, fully coalesced f32 stores ========
  // Two halves of 32 tokens; LDS as [32 tok][512 och] f32 (64KB), XOR-swizzled.
#pragma unroll
  for (int th = 0; th < 2; ++th) {
    __syncthreads();   // th=0: all waves done reading O; th=1: done reading half 0
#pragma unroll
    for (int mi = 0; mi < 4; ++mi)
#pragma unroll
      for (int jj = 0; jj < 2; ++jj) {
        const int tj = th * 2 + jj;
        const int tl = (tj * 16 + lr) & 31;                 // token within half
        const int ochb = (wv * 64 + mi * 16 + g * 4) * 4;   // byte offset of och
        *(f32x4*)(smem + tl * 2048 + (ochb ^ ((tl & 7) << 4))) = acc[mi][tj];
      }
    __syncthreads();
    // store: each wave-iteration writes 1KB contiguous (half a token's channels)
#pragma unroll
    for (int it = 0; it < 8; ++it) {
      const int task = it * 8 + wv;       // 0..63
      const int tl = task >> 1;           // 0..31
      const int hf = task & 1;            // which 1KB half of the 2KB token row
      const int ochb = hf * 1024 + l * 16;
      f32x4 v = *(const f32x4*)(smem + tl * 2048 + (ochb ^ ((tl & 7) << 4)));
      *(f32x4*)(out + (size_t)tok_global(blk, th * 32 + tl) * 512 + hf * 256 + l * 4) = v;
    }
  }
}

extern "C" void kernel_launch(void* const* d_in, const int* in_sizes, int n_in,
                              void* d_out, int out_size, void* d_ws, size_t ws_size,
                              hipStream_t stream) {
  const float* x  = (const float*)d_in[0];
  const float* wq = (const float*)d_in[1];
  const float* bq = (const float*)d_in[2];
  const float* wp = (const float*)d_in[3];
  const float* bp = (const float*)d_in[4];
  float* out = (float*)d_out;
  u16* wtq = (u16*)d_ws;            // qkv frag-major blob: 96 o_blks x 16 ks x 512
  u16* wtp = wtq + 512 * 1536;      // proj frag-major blob: 32 o_blks x 16 ks x 512

  prep_weights<<<2048, 512, 0, stream>>>(wq, wp, wtq, wtp);
  fused_win_attn<<<1024, 512, 0, stream>>>(x, bq, bp, wtq, wtp, out);
}